// Round 13
// baseline (183.843 us; speedup 1.0000x reference)
//
#include <hip/hip_runtime.h>
#include <math.h>

// MEASUREMENT ROUND v2: exact R8 kernel (best known, 80.4us) with npass=3
// and a compiler memory barrier per pass (asm volatile "memory") so the
// extra passes CANNOT be CSE/DSE'd away (R12's npass=2 was deduped: +3.4us
// proved the compiler removed pass 2). Each pass is a full load+compute+
// store sweep; dispatch ~240us -> enters rocprof top-5. Timed number is
// sacrificial; R8 remains the best-known kernel.
//
// Blur math: separable g=[0.25,0.75,0.75,0.25]:
//   out[2i]   = 0.25*X[i-1] + 0.75*X[i]
//   out[2i+1] = 0.75*X[i]   + 0.25*X[i+1]
// Wave = input row pair {2r,2r+1} -> out rows 4r..4r+3; line-dense stores
// (lane l owns cols [S+4l,S+4l+4) win1, [S+256+4l,..) win2, S templated).

template<int S>
__device__ __forceinline__ void hblend(float v0, float v1, float vm1,
                                       float vp0, float vp1, float q[4]) {
    if (S == 0) {
        q[0] = 0.25f*vm1 + 0.75f*v0;
        q[1] = 0.75f*v0  + 0.25f*v1;
        q[2] = 0.25f*v0  + 0.75f*v1;
        q[3] = 0.75f*v1  + 0.25f*vp0;
    } else if (S == 1) {
        q[0] = 0.75f*v0  + 0.25f*v1;
        q[1] = 0.25f*v0  + 0.75f*v1;
        q[2] = 0.75f*v1  + 0.25f*vp0;
        q[3] = 0.25f*v1  + 0.75f*vp0;
    } else if (S == 2) {
        q[0] = 0.25f*v0  + 0.75f*v1;
        q[1] = 0.75f*v1  + 0.25f*vp0;
        q[2] = 0.25f*v1  + 0.75f*vp0;
        q[3] = 0.75f*vp0 + 0.25f*vp1;
    } else {
        q[0] = 0.75f*v1  + 0.25f*vp0;
        q[1] = 0.25f*v1  + 0.75f*vp0;
        q[2] = 0.75f*vp0 + 0.25f*vp1;
        q[3] = 0.25f*vp0 + 0.75f*vp1;
    }
}

template<int S>
__device__ __forceinline__ void store_row(float* __restrict__ rp, int lane,
                                          int Wo, const float q1[4],
                                          const float q2[4],
                                          float v0lane, float v1lane) {
    *(float4*)(rp + S + 4 * lane) = make_float4(q1[0], q1[1], q1[2], q1[3]);
    int c0 = S + 256 + 4 * lane;
    if (c0 + 3 < Wo) {
        *(float4*)(rp + c0) = make_float4(q2[0], q2[1], q2[2], q2[3]);
    } else {
        if (c0     < Wo) rp[c0]     = q2[0];
        if (c0 + 1 < Wo) rp[c0 + 1] = q2[1];
        if (c0 + 2 < Wo) rp[c0 + 2] = q2[2];
        if (c0 + 3 < Wo) rp[c0 + 3] = q2[3];
    }
    if (S > 0 && lane == 0) {
        rp[0] = 0.75f * v0lane;
        if (S > 1) rp[1] = 0.75f * v0lane + 0.25f * v1lane;
        if (S > 2) rp[2] = 0.25f * v0lane + 0.75f * v1lane;
    }
}

template<int SE>
__device__ __forceinline__ void emit_pair(
    float2 a1, float2 b1, float2 c1, float2 a2, float2 b2, float2 c2,
    float w0, float wp, float* __restrict__ out, size_t be,
    int lane, int orow, int Ho, int Wo) {
    constexpr int SO = (SE + 1) & 3;

    float ve10 = w0*a1.x + 0.75f*b1.x, ve11 = w0*a1.y + 0.75f*b1.y;
    float ve20 = w0*a2.x + 0.75f*b2.x, ve21 = w0*a2.y + 0.75f*b2.y;
    float vo10 = 0.75f*b1.x + wp*c1.x, vo11 = 0.75f*b1.y + wp*c1.y;
    float vo20 = 0.75f*b2.x + wp*c2.x, vo21 = 0.75f*b2.y + wp*c2.y;

    float t;
    float vm1e1 = __shfl_up(ve11, 1);   if (lane == 0)  vm1e1 = 0.f;
    float vp0e1 = __shfl_down(ve10, 1);
    t = __shfl(ve20, 0);                if (lane == 63) vp0e1 = t;
    float vp1e1 = __shfl_down(ve11, 1);
    t = __shfl(ve21, 0);                if (lane == 63) vp1e1 = t;
    float vm1e2 = __shfl_up(ve21, 1);
    t = __shfl(ve11, 63);               if (lane == 0)  vm1e2 = t;
    float vp0e2 = __shfl_down(ve20, 1); if (lane == 63) vp0e2 = 0.f;
    float vp1e2 = __shfl_down(ve21, 1); if (lane == 63) vp1e2 = 0.f;
    float vm1o1 = __shfl_up(vo11, 1);   if (lane == 0)  vm1o1 = 0.f;
    float vp0o1 = __shfl_down(vo10, 1);
    t = __shfl(vo20, 0);                if (lane == 63) vp0o1 = t;
    float vp1o1 = __shfl_down(vo11, 1);
    t = __shfl(vo21, 0);                if (lane == 63) vp1o1 = t;
    float vm1o2 = __shfl_up(vo21, 1);
    t = __shfl(vo11, 63);               if (lane == 0)  vm1o2 = t;
    float vp0o2 = __shfl_down(vo20, 1); if (lane == 63) vp0o2 = 0.f;
    float vp1o2 = __shfl_down(vo21, 1); if (lane == 63) vp1o2 = 0.f;

    float q1[4], q2[4];
    float* re = out + be;
    hblend<SE>(ve10, ve11, vm1e1, vp0e1, vp1e1, q1);
    hblend<SE>(ve20, ve21, vm1e2, vp0e2, vp1e2, q2);
    store_row<SE>(re, lane, Wo, q1, q2, ve10, ve11);

    if (orow + 1 < Ho) {
        float* ro = re + Wo;
        hblend<SO>(vo10, vo11, vm1o1, vp0o1, vp1o1, q1);
        hblend<SO>(vo20, vo21, vm1o2, vp0o2, vp1o2, q2);
        store_row<SO>(ro, lane, Wo, q1, q2, vo10, vo11);
    }
}

__global__ __launch_bounds__(256) void blur_up2_kernel(
    const float* __restrict__ x, float* __restrict__ out,
    int H, int W, int Ho, int Wo, int npass) {
    int lane = threadIdx.x;                   // 0..63
    int r = blockIdx.y * 4 + threadIdx.y;     // 0..127: input rows {2r, 2r+1}
    int nc = blockIdx.z;
    int i0 = 2 * r, i1 = 2 * r + 1;

#pragma unroll 1
    for (int pass = 0; pass < npass; ++pass) {
        // Full compiler memory barrier: pass N stores are observable, pass
        // N+1 loads can't be CSE'd. Emits no instructions.
        asm volatile("" ::: "memory");

        const float* xp = x + (size_t)nc * H * W;
        const float2* prm = (const float2*)(xp + (i0 > 0 ? i0 - 1 : 0) * W);
        const float2* pr0 = (const float2*)(xp + i0 * W);
        const float2* pr1 = (const float2*)(xp + i1 * W);
        const float2* prp = (const float2*)(xp + (i1 < H - 1 ? i1 + 1 : H - 1) * W);

        float2 m1 = prm[lane], m2 = prm[64 + lane];
        float2 z01 = pr0[lane], z02 = pr0[64 + lane];
        float2 z11 = pr1[lane], z12 = pr1[64 + lane];
        float2 p1 = prp[lane], p2 = prp[64 + lane];

        float w_top = (i0 > 0)     ? 0.25f : 0.0f;
        float w_bot = (i1 < H - 1) ? 0.25f : 0.0f;

        size_t obase = (size_t)nc * Ho * Wo;
        size_t be0 = obase + (size_t)(2 * i0) * Wo;   // output row 4r
        size_t be1 = be0 + 2 * (size_t)Wo;            // output row 4r+2
        int S0 = (int)((4 - (be0 & 3)) & 3);          // wave-uniform

        switch (S0) {
            case 0:
                emit_pair<0>(m1, z01, z11, m2, z02, z12, w_top, 0.25f, out, be0, lane, 2*i0, Ho, Wo);
                emit_pair<2>(z01, z11, p1, z02, z12, p2, 0.25f, w_bot, out, be1, lane, 2*i1, Ho, Wo);
                break;
            case 1:
                emit_pair<1>(m1, z01, z11, m2, z02, z12, w_top, 0.25f, out, be0, lane, 2*i0, Ho, Wo);
                emit_pair<3>(z01, z11, p1, z02, z12, p2, 0.25f, w_bot, out, be1, lane, 2*i1, Ho, Wo);
                break;
            case 2:
                emit_pair<2>(m1, z01, z11, m2, z02, z12, w_top, 0.25f, out, be0, lane, 2*i0, Ho, Wo);
                emit_pair<0>(z01, z11, p1, z02, z12, p2, 0.25f, w_bot, out, be1, lane, 2*i1, Ho, Wo);
                break;
            default:
                emit_pair<3>(m1, z01, z11, m2, z02, z12, w_top, 0.25f, out, be0, lane, 2*i0, Ho, Wo);
                emit_pair<1>(z01, z11, p1, z02, z12, p2, 0.25f, w_bot, out, be1, lane, 2*i1, Ho, Wo);
                break;
        }
    }
}

extern "C" void kernel_launch(void* const* d_in, const int* in_sizes, int n_in,
                              void* d_out, int out_size, void* d_ws, size_t ws_size,
                              hipStream_t stream) {
    const float* x = (const float*)d_in[0];
    float* out = (float*)d_out;

    const int H = 256, W = 256;
    int NC = in_sizes[0] / (H * W);  // 256

    int hw_out = out_size / NC;
    int Wo = (int)(sqrt((double)hw_out) + 0.5);
    int Ho = hw_out / Wo;

    dim3 block(64, 4);
    dim3 grid(1, 32, NC);   // 128 row-pairs / 4 per block
    blur_up2_kernel<<<grid, block, 0, stream>>>(x, out, H, W, Ho, Wo, 3);
}

// Round 14
// 79.853 us; speedup vs baseline: 2.3023x; 2.3023x over previous
//
#include <hip/hip_runtime.h>
#include <math.h>

// StyleGAN2 2x upsample blur (upfirdn2d, up=2, f=[1,3,3,1], gain=4).
// Separable: g=[0.25,0.75,0.75,0.25]:
//   out[2i]   = 0.25*X[i-1] + 0.75*X[i]
//   out[2i+1] = 0.75*X[i]   + 0.25*X[i+1]
//
// R13 counters: WRITE=252MB/pass (ideal, no inflation), steady-state passes
// run at the ~6.3TB/s fabric ceiling; single-pass loses ~25us to unhidden
// cold-read latency (one-shot waves stall on their 8 loads, then die).
// THIS ROUND: persistent 4-unit waves + rolling register row-window +
// software prefetch. Wave w owns row-pairs r=4t..4t+3 (16 output rows);
// window rows A=2r-1,B=2r,C=2r+1,D=2r+2 (x2 col-windows); per unit prefetch
// rows 2r+3,2r+4 BEFORE emitting stores, rotate A<-C,B<-D,C<-E,D<-F.
// Load issue drops 16->10 rows/wave; load latency hides under stores.
// 4*Wo % 4 == 0 -> alignment shift S0 constant per wave -> one static
// dispatch. Store path (line-dense, S-templated) unchanged from R8.

template<int S>
__device__ __forceinline__ void hblend(float v0, float v1, float vm1,
                                       float vp0, float vp1, float q[4]) {
    if (S == 0) {
        q[0] = 0.25f*vm1 + 0.75f*v0;
        q[1] = 0.75f*v0  + 0.25f*v1;
        q[2] = 0.25f*v0  + 0.75f*v1;
        q[3] = 0.75f*v1  + 0.25f*vp0;
    } else if (S == 1) {
        q[0] = 0.75f*v0  + 0.25f*v1;
        q[1] = 0.25f*v0  + 0.75f*v1;
        q[2] = 0.75f*v1  + 0.25f*vp0;
        q[3] = 0.25f*v1  + 0.75f*vp0;
    } else if (S == 2) {
        q[0] = 0.25f*v0  + 0.75f*v1;
        q[1] = 0.75f*v1  + 0.25f*vp0;
        q[2] = 0.25f*v1  + 0.75f*vp0;
        q[3] = 0.75f*vp0 + 0.25f*vp1;
    } else {
        q[0] = 0.75f*v1  + 0.25f*vp0;
        q[1] = 0.25f*v1  + 0.75f*vp0;
        q[2] = 0.75f*vp0 + 0.25f*vp1;
        q[3] = 0.25f*vp0 + 0.75f*vp1;
    }
}

template<int S>
__device__ __forceinline__ void store_row(float* __restrict__ rp, int lane,
                                          int Wo, const float q1[4],
                                          const float q2[4],
                                          float v0lane, float v1lane) {
    *(float4*)(rp + S + 4 * lane) = make_float4(q1[0], q1[1], q1[2], q1[3]);
    int c0 = S + 256 + 4 * lane;
    if (c0 + 3 < Wo) {
        *(float4*)(rp + c0) = make_float4(q2[0], q2[1], q2[2], q2[3]);
    } else {
        if (c0     < Wo) rp[c0]     = q2[0];
        if (c0 + 1 < Wo) rp[c0 + 1] = q2[1];
        if (c0 + 2 < Wo) rp[c0 + 2] = q2[2];
        if (c0 + 3 < Wo) rp[c0 + 3] = q2[3];
    }
    if (S > 0 && lane == 0) {
        rp[0] = 0.75f * v0lane;
        if (S > 1) rp[1] = 0.75f * v0lane + 0.25f * v1lane;
        if (S > 2) rp[2] = 0.25f * v0lane + 0.75f * v1lane;
    }
}

// One input row triple (a,b,c = rows i-1,i,i+1, two col-windows each) ->
// output rows {orow, orow+1}. w0/wp are folded row-boundary masks.
template<int SE>
__device__ __forceinline__ void emit_pair(
    float2 a1, float2 b1, float2 c1, float2 a2, float2 b2, float2 c2,
    float w0, float wp, float* __restrict__ out, size_t be,
    int lane, int orow, int Ho, int Wo) {
    constexpr int SO = (SE + 1) & 3;

    float ve10 = w0*a1.x + 0.75f*b1.x, ve11 = w0*a1.y + 0.75f*b1.y;
    float ve20 = w0*a2.x + 0.75f*b2.x, ve21 = w0*a2.y + 0.75f*b2.y;
    float vo10 = 0.75f*b1.x + wp*c1.x, vo11 = 0.75f*b1.y + wp*c1.y;
    float vo20 = 0.75f*b2.x + wp*c2.x, vo21 = 0.75f*b2.y + wp*c2.y;

    float t;
    float vm1e1 = __shfl_up(ve11, 1);   if (lane == 0)  vm1e1 = 0.f;
    float vp0e1 = __shfl_down(ve10, 1);
    t = __shfl(ve20, 0);                if (lane == 63) vp0e1 = t;
    float vp1e1 = __shfl_down(ve11, 1);
    t = __shfl(ve21, 0);                if (lane == 63) vp1e1 = t;
    float vm1e2 = __shfl_up(ve21, 1);
    t = __shfl(ve11, 63);               if (lane == 0)  vm1e2 = t;
    float vp0e2 = __shfl_down(ve20, 1); if (lane == 63) vp0e2 = 0.f;
    float vp1e2 = __shfl_down(ve21, 1); if (lane == 63) vp1e2 = 0.f;
    float vm1o1 = __shfl_up(vo11, 1);   if (lane == 0)  vm1o1 = 0.f;
    float vp0o1 = __shfl_down(vo10, 1);
    t = __shfl(vo20, 0);                if (lane == 63) vp0o1 = t;
    float vp1o1 = __shfl_down(vo11, 1);
    t = __shfl(vo21, 0);                if (lane == 63) vp1o1 = t;
    float vm1o2 = __shfl_up(vo21, 1);
    t = __shfl(vo11, 63);               if (lane == 0)  vm1o2 = t;
    float vp0o2 = __shfl_down(vo20, 1); if (lane == 63) vp0o2 = 0.f;
    float vp1o2 = __shfl_down(vo21, 1); if (lane == 63) vp1o2 = 0.f;

    float q1[4], q2[4];
    float* re = out + be;
    hblend<SE>(ve10, ve11, vm1e1, vp0e1, vp1e1, q1);
    hblend<SE>(ve20, ve21, vm1e2, vp0e2, vp1e2, q2);
    store_row<SE>(re, lane, Wo, q1, q2, ve10, ve11);

    if (orow + 1 < Ho) {
        float* ro = re + Wo;
        hblend<SO>(vo10, vo11, vm1o1, vp0o1, vp1o1, q1);
        hblend<SO>(vo20, vo21, vm1o2, vp0o2, vp1o2, q2);
        store_row<SO>(ro, lane, Wo, q1, q2, vo10, vo11);
    }
}

__device__ __forceinline__ void ldrow(const float* __restrict__ xp, int row,
                                      int lane, int W, float2& w1, float2& w2) {
    const float2* p = (const float2*)(xp + row * W);
    w1 = p[lane];
    w2 = p[64 + lane];
}

template<int S0>
__device__ __forceinline__ void run_wave(const float* __restrict__ xp,
                                         float* __restrict__ out, size_t obase,
                                         int rbase, int lane,
                                         int H, int W, int Ho, int Wo) {
    // rolling window rows: A=2r-1, B=2r, C=2r+1, D=2r+2 (two col-windows)
    float2 A1, A2, B1, B2, C1, C2, D1, D2, E1, E2, F1, F2;
    int r0 = rbase;
    ldrow(xp, 2*r0 - 1 > 0 ? 2*r0 - 1 : 0, lane, W, A1, A2);
    ldrow(xp, 2*r0,                        lane, W, B1, B2);
    ldrow(xp, 2*r0 + 1,                    lane, W, C1, C2);
    ldrow(xp, 2*r0 + 2 < H ? 2*r0 + 2 : H - 1, lane, W, D1, D2);

#pragma unroll
    for (int k = 0; k < 4; ++k) {
        int rr = rbase + k;
        if (k < 3) {   // prefetch next unit's two new rows BEFORE stores
            ldrow(xp, 2*rr + 3, lane, W, E1, E2);
            ldrow(xp, 2*rr + 4 < H ? 2*rr + 4 : H - 1, lane, W, F1, F2);
        }
        float w_top = (rr > 0) ? 0.25f : 0.0f;
        float w_bot = (2*rr + 1 < H - 1) ? 0.25f : 0.0f;
        size_t be0 = obase + (size_t)(4 * rr) * Wo;
        size_t be1 = be0 + 2 * (size_t)Wo;
        emit_pair<S0>(A1, B1, C1, A2, B2, C2, w_top, 0.25f,
                      out, be0, lane, 4 * rr, Ho, Wo);
        emit_pair<(S0 + 2) & 3>(B1, C1, D1, B2, C2, D2, 0.25f, w_bot,
                                out, be1, lane, 4 * rr + 2, Ho, Wo);
        A1 = C1; A2 = C2; B1 = D1; B2 = D2;
        C1 = E1; C2 = E2; D1 = F1; D2 = F2;
    }
}

__global__ __launch_bounds__(256) void blur_up2_kernel(
    const float* __restrict__ x, float* __restrict__ out,
    int H, int W, int Ho, int Wo) {
    int lane = threadIdx.x;                    // 0..63
    int w = blockIdx.x * 4 + threadIdx.y;      // global wave id
    int ch = w >> 5;                           // channel (32 waves/channel)
    int rbase = (w & 31) * 4;                  // first row-pair of this wave

    const float* xp = x + (size_t)ch * H * W;
    size_t obase = (size_t)ch * Ho * Wo;
    size_t be0 = obase + (size_t)(4 * rbase) * Wo;
    int S0 = (int)((4 - (be0 & 3)) & 3);       // constant across the 4 units
    switch (S0) {
        case 0:  run_wave<0>(xp, out, obase, rbase, lane, H, W, Ho, Wo); break;
        case 1:  run_wave<1>(xp, out, obase, rbase, lane, H, W, Ho, Wo); break;
        case 2:  run_wave<2>(xp, out, obase, rbase, lane, H, W, Ho, Wo); break;
        default: run_wave<3>(xp, out, obase, rbase, lane, H, W, Ho, Wo); break;
    }
}

extern "C" void kernel_launch(void* const* d_in, const int* in_sizes, int n_in,
                              void* d_out, int out_size, void* d_ws, size_t ws_size,
                              hipStream_t stream) {
    const float* x = (const float*)d_in[0];
    float* out = (float*)d_out;

    const int H = 256, W = 256;
    int NC = in_sizes[0] / (H * W);  // 256

    int hw_out = out_size / NC;
    int Wo = (int)(sqrt((double)hw_out) + 0.5);
    int Ho = hw_out / Wo;

    dim3 block(64, 4);
    dim3 grid(NC * 8);               // 8 blocks/channel = 32 waves/channel
    blur_up2_kernel<<<grid, block, 0, stream>>>(x, out, H, W, Ho, Wo);
}

// Round 15
// 74.113 us; speedup vs baseline: 2.4806x; 1.0774x over previous
//
#include <hip/hip_runtime.h>
#include <math.h>

// StyleGAN2 2x upsample blur (upfirdn2d, up=2, f=[1,3,3,1], gain=4).
// TWO-KERNEL STREAM SEGREGATION EXPERIMENT:
//   K1 (warm): pure-read sweep of the 67MB input at full read BW -> input
//       lands in the 256MB L3. Per-block checksum written to d_ws (guarded
//       by ws_size) so the loads are not DCE-able; deterministic.
//   K2 (main): EXACT R14 kernel (best known, 79.85us). With input L3-hot,
//       R13's counters say the write stream runs ~4.9-7 TB/s instead of
//       the cold-mixed 4.2.
// Rationale: R8 (1 stall/wave) == R14 (4 stalls/wave) == 80us proved
// per-wave latency structure is irrelevant; fill=7.1TB/s vs hot-pass 55us
// vs cold-pass 80us says the cost is read-stream/write-stream interference
// at the memory system. Time-segregating the streams is the one untested
// lever.

// ---------------- K1: warm ----------------
__global__ __launch_bounds__(256) void warm_kernel(
    const float4* __restrict__ x, int n4, float* __restrict__ ws, int nws) {
    int tid = blockIdx.x * 256 + threadIdx.x;
    int stride = gridDim.x * 256;
    float s = 0.f;
    for (int i = tid; i < n4; i += stride) {
        float4 v = x[i];
        s += v.x + v.y + v.z + v.w;
    }
    // wave64 reduce
    for (int off = 32; off > 0; off >>= 1) s += __shfl_down(s, off);
    __shared__ float sm[4];
    if ((threadIdx.x & 63) == 0) sm[threadIdx.x >> 6] = s;
    __syncthreads();
    if (threadIdx.x == 0) {
        float t = sm[0] + sm[1] + sm[2] + sm[3];
        if ((int)blockIdx.x < nws) ws[blockIdx.x] = t;  // defeat DCE
    }
}

// ---------------- K2: exact R14 main ----------------
template<int S>
__device__ __forceinline__ void hblend(float v0, float v1, float vm1,
                                       float vp0, float vp1, float q[4]) {
    if (S == 0) {
        q[0] = 0.25f*vm1 + 0.75f*v0;
        q[1] = 0.75f*v0  + 0.25f*v1;
        q[2] = 0.25f*v0  + 0.75f*v1;
        q[3] = 0.75f*v1  + 0.25f*vp0;
    } else if (S == 1) {
        q[0] = 0.75f*v0  + 0.25f*v1;
        q[1] = 0.25f*v0  + 0.75f*v1;
        q[2] = 0.75f*v1  + 0.25f*vp0;
        q[3] = 0.25f*v1  + 0.75f*vp0;
    } else if (S == 2) {
        q[0] = 0.25f*v0  + 0.75f*v1;
        q[1] = 0.75f*v1  + 0.25f*vp0;
        q[2] = 0.25f*v1  + 0.75f*vp0;
        q[3] = 0.75f*vp0 + 0.25f*vp1;
    } else {
        q[0] = 0.75f*v1  + 0.25f*vp0;
        q[1] = 0.25f*v1  + 0.75f*vp0;
        q[2] = 0.75f*vp0 + 0.25f*vp1;
        q[3] = 0.25f*vp0 + 0.75f*vp1;
    }
}

template<int S>
__device__ __forceinline__ void store_row(float* __restrict__ rp, int lane,
                                          int Wo, const float q1[4],
                                          const float q2[4],
                                          float v0lane, float v1lane) {
    *(float4*)(rp + S + 4 * lane) = make_float4(q1[0], q1[1], q1[2], q1[3]);
    int c0 = S + 256 + 4 * lane;
    if (c0 + 3 < Wo) {
        *(float4*)(rp + c0) = make_float4(q2[0], q2[1], q2[2], q2[3]);
    } else {
        if (c0     < Wo) rp[c0]     = q2[0];
        if (c0 + 1 < Wo) rp[c0 + 1] = q2[1];
        if (c0 + 2 < Wo) rp[c0 + 2] = q2[2];
        if (c0 + 3 < Wo) rp[c0 + 3] = q2[3];
    }
    if (S > 0 && lane == 0) {
        rp[0] = 0.75f * v0lane;
        if (S > 1) rp[1] = 0.75f * v0lane + 0.25f * v1lane;
        if (S > 2) rp[2] = 0.25f * v0lane + 0.75f * v1lane;
    }
}

template<int SE>
__device__ __forceinline__ void emit_pair(
    float2 a1, float2 b1, float2 c1, float2 a2, float2 b2, float2 c2,
    float w0, float wp, float* __restrict__ out, size_t be,
    int lane, int orow, int Ho, int Wo) {
    constexpr int SO = (SE + 1) & 3;

    float ve10 = w0*a1.x + 0.75f*b1.x, ve11 = w0*a1.y + 0.75f*b1.y;
    float ve20 = w0*a2.x + 0.75f*b2.x, ve21 = w0*a2.y + 0.75f*b2.y;
    float vo10 = 0.75f*b1.x + wp*c1.x, vo11 = 0.75f*b1.y + wp*c1.y;
    float vo20 = 0.75f*b2.x + wp*c2.x, vo21 = 0.75f*b2.y + wp*c2.y;

    float t;
    float vm1e1 = __shfl_up(ve11, 1);   if (lane == 0)  vm1e1 = 0.f;
    float vp0e1 = __shfl_down(ve10, 1);
    t = __shfl(ve20, 0);                if (lane == 63) vp0e1 = t;
    float vp1e1 = __shfl_down(ve11, 1);
    t = __shfl(ve21, 0);                if (lane == 63) vp1e1 = t;
    float vm1e2 = __shfl_up(ve21, 1);
    t = __shfl(ve11, 63);               if (lane == 0)  vm1e2 = t;
    float vp0e2 = __shfl_down(ve20, 1); if (lane == 63) vp0e2 = 0.f;
    float vp1e2 = __shfl_down(ve21, 1); if (lane == 63) vp1e2 = 0.f;
    float vm1o1 = __shfl_up(vo11, 1);   if (lane == 0)  vm1o1 = 0.f;
    float vp0o1 = __shfl_down(vo10, 1);
    t = __shfl(vo20, 0);                if (lane == 63) vp0o1 = t;
    float vp1o1 = __shfl_down(vo11, 1);
    t = __shfl(vo21, 0);                if (lane == 63) vp1o1 = t;
    float vm1o2 = __shfl_up(vo21, 1);
    t = __shfl(vo11, 63);               if (lane == 0)  vm1o2 = t;
    float vp0o2 = __shfl_down(vo20, 1); if (lane == 63) vp0o2 = 0.f;
    float vp1o2 = __shfl_down(vo21, 1); if (lane == 63) vp1o2 = 0.f;

    float q1[4], q2[4];
    float* re = out + be;
    hblend<SE>(ve10, ve11, vm1e1, vp0e1, vp1e1, q1);
    hblend<SE>(ve20, ve21, vm1e2, vp0e2, vp1e2, q2);
    store_row<SE>(re, lane, Wo, q1, q2, ve10, ve11);

    if (orow + 1 < Ho) {
        float* ro = re + Wo;
        hblend<SO>(vo10, vo11, vm1o1, vp0o1, vp1o1, q1);
        hblend<SO>(vo20, vo21, vm1o2, vp0o2, vp1o2, q2);
        store_row<SO>(ro, lane, Wo, q1, q2, vo10, vo11);
    }
}

__device__ __forceinline__ void ldrow(const float* __restrict__ xp, int row,
                                      int lane, int W, float2& w1, float2& w2) {
    const float2* p = (const float2*)(xp + row * W);
    w1 = p[lane];
    w2 = p[64 + lane];
}

template<int S0>
__device__ __forceinline__ void run_wave(const float* __restrict__ xp,
                                         float* __restrict__ out, size_t obase,
                                         int rbase, int lane,
                                         int H, int W, int Ho, int Wo) {
    float2 A1, A2, B1, B2, C1, C2, D1, D2, E1, E2, F1, F2;
    int r0 = rbase;
    ldrow(xp, 2*r0 - 1 > 0 ? 2*r0 - 1 : 0, lane, W, A1, A2);
    ldrow(xp, 2*r0,                        lane, W, B1, B2);
    ldrow(xp, 2*r0 + 1,                    lane, W, C1, C2);
    ldrow(xp, 2*r0 + 2 < H ? 2*r0 + 2 : H - 1, lane, W, D1, D2);

#pragma unroll
    for (int k = 0; k < 4; ++k) {
        int rr = rbase + k;
        if (k < 3) {
            ldrow(xp, 2*rr + 3, lane, W, E1, E2);
            ldrow(xp, 2*rr + 4 < H ? 2*rr + 4 : H - 1, lane, W, F1, F2);
        }
        float w_top = (rr > 0) ? 0.25f : 0.0f;
        float w_bot = (2*rr + 1 < H - 1) ? 0.25f : 0.0f;
        size_t be0 = obase + (size_t)(4 * rr) * Wo;
        size_t be1 = be0 + 2 * (size_t)Wo;
        emit_pair<S0>(A1, B1, C1, A2, B2, C2, w_top, 0.25f,
                      out, be0, lane, 4 * rr, Ho, Wo);
        emit_pair<(S0 + 2) & 3>(B1, C1, D1, B2, C2, D2, 0.25f, w_bot,
                                out, be1, lane, 4 * rr + 2, Ho, Wo);
        A1 = C1; A2 = C2; B1 = D1; B2 = D2;
        C1 = E1; C2 = E2; D1 = F1; D2 = F2;
    }
}

__global__ __launch_bounds__(256) void blur_up2_kernel(
    const float* __restrict__ x, float* __restrict__ out,
    int H, int W, int Ho, int Wo) {
    int lane = threadIdx.x;
    int w = blockIdx.x * 4 + threadIdx.y;
    int ch = w >> 5;
    int rbase = (w & 31) * 4;

    const float* xp = x + (size_t)ch * H * W;
    size_t obase = (size_t)ch * Ho * Wo;
    size_t be0 = obase + (size_t)(4 * rbase) * Wo;
    int S0 = (int)((4 - (be0 & 3)) & 3);
    switch (S0) {
        case 0:  run_wave<0>(xp, out, obase, rbase, lane, H, W, Ho, Wo); break;
        case 1:  run_wave<1>(xp, out, obase, rbase, lane, H, W, Ho, Wo); break;
        case 2:  run_wave<2>(xp, out, obase, rbase, lane, H, W, Ho, Wo); break;
        default: run_wave<3>(xp, out, obase, rbase, lane, H, W, Ho, Wo); break;
    }
}

extern "C" void kernel_launch(void* const* d_in, const int* in_sizes, int n_in,
                              void* d_out, int out_size, void* d_ws, size_t ws_size,
                              hipStream_t stream) {
    const float* x = (const float*)d_in[0];
    float* out = (float*)d_out;

    const int H = 256, W = 256;
    int NC = in_sizes[0] / (H * W);  // 256

    int hw_out = out_size / NC;
    int Wo = (int)(sqrt((double)hw_out) + 0.5);
    int Ho = hw_out / Wo;

    // K1: pure-read warm sweep of the input into L3
    int n4 = in_sizes[0] / 4;
    int nws = (int)(ws_size / sizeof(float));
    warm_kernel<<<2048, 256, 0, stream>>>((const float4*)x, n4,
                                          (float*)d_ws, nws);

    // K2: exact R14 blur
    dim3 block(64, 4);
    dim3 grid(NC * 8);
    blur_up2_kernel<<<grid, block, 0, stream>>>(x, out, H, W, Ho, Wo);
}